// Round 1
// baseline (507.955 us; speedup 1.0000x reference)
//
#include <hip/hip_runtime.h>

#define B 32
#define T 8192
#define H 128
#define ROWS_PER_BLOCK 128

// ---------------------------------------------------------------------------
// Kernel 1: u[b][h] = b_attn[h] + dot(W_attn[h, 0:H], hidden[b, :])
// Grid: B blocks x H threads. Tiny (32*128*128 FLOP).
// ---------------------------------------------------------------------------
__global__ void k_precompute_u(const float* __restrict__ hidden,
                               const float* __restrict__ W_attn,
                               const float* __restrict__ b_attn,
                               float* __restrict__ u) {
    const int b = blockIdx.x;
    const int h = threadIdx.x;
    __shared__ float hrow[H];
    hrow[h] = hidden[b * H + h];
    __syncthreads();
    const float* w = W_attn + (size_t)h * (2 * H);  // W1 row h
    float acc = b_attn[h];
#pragma unroll
    for (int k = 0; k < H; ++k) acc = fmaf(w[k], hrow[k], acc);
    u[b * H + h] = acc;
}

// ---------------------------------------------------------------------------
// Kernel 2: scores[b][t] = sum_h relu(u[b][h] + dot(W2[h,:], enc[t,b,:])) * v[h]
//
// Layout: enc is [T,B,H] so row r = t*B + b is 128 contiguous floats.
// Each 128-thread block: thread h permanently holds W2[h][0:128] in VGPRs
// (loaded once per block, L2-hot). All threads of the block walk the same
// row r together: the row data is wave-uniform (address depends only on
// blockIdx + loop counter), so loads scalarize / coalesce to one fetch.
// 128 FMAs per thread per row with 4 independent accumulators (ILP for the
// 4-cycle FMA dep latency), then relu * v[h] and a 2-wave reduction.
// Scores are written into d_out ([B][T] == out layout).
// ---------------------------------------------------------------------------
__global__ __launch_bounds__(128) void k_scores(
    const float* __restrict__ enc,     // [T*B*H]
    const float* __restrict__ W_attn,  // [H][2H]
    const float* __restrict__ u,       // [B][H]
    const float* __restrict__ v,       // [H]
    float* __restrict__ scores)        // [B][T]
{
    const int h    = threadIdx.x;   // 0..127 = output feature
    const int lane = h & 63;
    const int wid  = h >> 6;

    // --- W2 row h into registers (32 x dwordx4) ---
    float w2[H];
    {
        const float4* wp = (const float4*)(W_attn + (size_t)h * (2 * H) + H);
#pragma unroll
        for (int i = 0; i < H / 4; ++i) {
            float4 q = wp[i];
            w2[4 * i + 0] = q.x; w2[4 * i + 1] = q.y;
            w2[4 * i + 2] = q.z; w2[4 * i + 3] = q.w;
        }
    }
    const float vh = v[h];

    __shared__ float part[2];

    const int r0 = blockIdx.x * ROWS_PER_BLOCK;
    for (int i = 0; i < ROWS_PER_BLOCK; ++i) {
        const int r  = r0 + i;
        const int rb = r & (B - 1);   // b  (r = t*B + b)
        const int rt = r >> 5;        // t
        const float uval = u[rb * H + h];   // coalesced, L1-hot (16 KB total)

        const float4* xp = (const float4*)(enc + (size_t)r * H);
        float a0 = 0.f, a1 = 0.f, a2 = 0.f, a3 = 0.f;
#pragma unroll
        for (int c = 0; c < H / 4; ++c) {
            float4 q = xp[c];          // wave-uniform address
            a0 = fmaf(q.x, w2[4 * c + 0], a0);
            a1 = fmaf(q.y, w2[4 * c + 1], a1);
            a2 = fmaf(q.z, w2[4 * c + 2], a2);
            a3 = fmaf(q.w, w2[4 * c + 3], a3);
        }
        float e = ((a0 + a1) + (a2 + a3)) + uval;
        float contrib = fmaxf(e, 0.f) * vh;

        // reduce over 128 threads: 6-step wave shuffle + 2-slot LDS combine
#pragma unroll
        for (int off = 32; off >= 1; off >>= 1)
            contrib += __shfl_xor(contrib, off);
        if (lane == 0) part[wid] = contrib;
        __syncthreads();
        if (h == 0) scores[(size_t)rb * T + rt] = part[0] + part[1];
        __syncthreads();
    }
}

// ---------------------------------------------------------------------------
// Kernel 3: ragged masked softmax per b, in-place on d_out.
// Grid: B blocks x 1024 threads.
// ---------------------------------------------------------------------------
__global__ __launch_bounds__(1024) void k_softmax(
    float* __restrict__ out,           // [B][T], holds scores on entry
    const int* __restrict__ len_seq)
{
    const int b    = blockIdx.x;
    const int tid  = threadIdx.x;
    const int lane = tid & 63;
    const int wid  = tid >> 6;
    const int len  = len_seq[b];
    float* s = out + (size_t)b * T;

    __shared__ float red[16];

    // ---- pass 1: max over valid t ----
    float m = -1e30f;
    for (int t = tid; t < len; t += 1024) m = fmaxf(m, s[t]);
#pragma unroll
    for (int off = 32; off >= 1; off >>= 1) m = fmaxf(m, __shfl_xor(m, off));
    if (lane == 0) red[wid] = m;
    __syncthreads();
    if (wid == 0) {
        float x = (lane < 16) ? red[lane] : -1e30f;
#pragma unroll
        for (int off = 8; off >= 1; off >>= 1) x = fmaxf(x, __shfl_xor(x, off));
        if (lane == 0) red[0] = x;
    }
    __syncthreads();
    m = red[0];
    __syncthreads();   // red about to be reused

    // ---- pass 2: sum of exp over valid t ----
    float sum = 0.f;
    for (int t = tid; t < len; t += 1024) sum += __expf(s[t] - m);
#pragma unroll
    for (int off = 32; off >= 1; off >>= 1) sum += __shfl_xor(sum, off);
    if (lane == 0) red[wid] = sum;
    __syncthreads();
    if (wid == 0) {
        float x = (lane < 16) ? red[lane] : 0.f;
#pragma unroll
        for (int off = 8; off >= 1; off >>= 1) x += __shfl_xor(x, off);
        if (lane == 0) red[0] = x;
    }
    __syncthreads();
    const float inv = 1.0f / red[0];

    // ---- pass 3: write normalized probs, zeros beyond len ----
    for (int t = tid; t < T; t += 1024) {
        float val = (t < len) ? __expf(s[t] - m) * inv : 0.0f;
        s[t] = val;
    }
}

// ---------------------------------------------------------------------------
extern "C" void kernel_launch(void* const* d_in, const int* in_sizes, int n_in,
                              void* d_out, int out_size, void* d_ws, size_t ws_size,
                              hipStream_t stream) {
    const float* hidden = (const float*)d_in[0];  // [B,H]
    const float* enc    = (const float*)d_in[1];  // [T,B,H]
    const int*   len    = (const int*)d_in[2];    // [B]
    const float* W      = (const float*)d_in[3];  // [H, 2H]
    const float* bb     = (const float*)d_in[4];  // [H]
    const float* v      = (const float*)d_in[5];  // [H]

    float* out  = (float*)d_out;   // [B,1,T] == [B][T]
    float* u_ws = (float*)d_ws;    // B*H floats = 16 KB

    k_precompute_u<<<B, H, 0, stream>>>(hidden, W, bb, u_ws);

    k_scores<<<(T * B) / ROWS_PER_BLOCK, H, 0, stream>>>(enc, W, u_ws, v, out);

    k_softmax<<<B, 1024, 0, stream>>>(out, len);
}

// Round 2
// 213.791 us; speedup vs baseline: 2.3759x; 2.3759x over previous
//
#include <hip/hip_runtime.h>

#define B 32
#define T 8192
#define H 128
#define TPB 256          // threads per scores-block; each thread owns one row (one t)

// ---------------------------------------------------------------------------
// Kernel 1: u[b][h] = b_attn[h] + dot(W1[h,:], hidden[b,:])   (tiny)
// ---------------------------------------------------------------------------
__global__ void k_precompute_u(const float* __restrict__ hidden,
                               const float* __restrict__ W_attn,
                               const float* __restrict__ b_attn,
                               float* __restrict__ u) {
    const int b = blockIdx.x;
    const int h = threadIdx.x;
    __shared__ float hrow[H];
    hrow[h] = hidden[b * H + h];
    __syncthreads();
    const float* w = W_attn + (size_t)h * (2 * H);  // W1 row h
    float acc = b_attn[h];
#pragma unroll
    for (int k = 0; k < H; ++k) acc = fmaf(w[k], hrow[k], acc);
    u[b * H + h] = acc;
}

// ---------------------------------------------------------------------------
// Kernel 2: scores[b][t] = sum_h relu(u[b][h] + dot(W2[h,:], enc[t*B+b,:])) * v[h]
//
// One thread == one row (t); one b per block (blockIdx.y). Thread holds its
// enc row in 128 VGPRs. W2 (64 KB fp32) staged in LDS once per block; the
// h-loop reads W2 rows at wave-uniform addresses -> LDS broadcast, no
// conflicts, no cross-lane reduction, no barriers in the hot loop.
// Output store is coalesced (lane i -> t0+i).
// ---------------------------------------------------------------------------
__global__ __launch_bounds__(TPB) void k_scores(
    const float* __restrict__ enc,     // [T*B*H]
    const float* __restrict__ W_attn,  // [H][2H]
    const float* __restrict__ u,       // [B][H]
    const float* __restrict__ v,       // [H]
    float* __restrict__ scores)        // [B][T]
{
    __shared__ float w2[H * H];        // 64 KB exactly; w2[h*H + k]

    const int tid = threadIdx.x;
    const int b   = blockIdx.y;
    const int t   = blockIdx.x * TPB + tid;

    // --- stage W2 -> LDS (W2[h][k] = W_attn[h][H + k]) ---
    for (int j = tid; j < H * (H / 4); j += TPB) {   // 4096 float4 / 256 thr = 16 iters
        const int h  = j >> 5;                       // 32 float4 per row
        const int c4 = j & 31;
        const float4 q = *(const float4*)(W_attn + (size_t)h * (2 * H) + H + 4 * c4);
        *(float4*)(&w2[h * H + 4 * c4]) = q;
    }
    __syncthreads();

    // --- load this thread's enc row into registers (32 x dwordx4) ---
    float x[H];
    {
        const float4* xp = (const float4*)(enc + (size_t)(t * B + b) * H);
#pragma unroll
        for (int c = 0; c < H / 4; ++c) {
            const float4 q = xp[c];
            x[4 * c + 0] = q.x; x[4 * c + 1] = q.y;
            x[4 * c + 2] = q.z; x[4 * c + 3] = q.w;
        }
    }

    const float* ub = u + b * H;
    float score = 0.0f;
    for (int h = 0; h < H; ++h) {
        const float* wr = &w2[h * H];
        float a0 = ub[h], a1 = 0.f, a2 = 0.f, a3 = 0.f;   // 4 independent chains
#pragma unroll
        for (int c = 0; c < H / 4; ++c) {
            const float4 q = *(const float4*)(wr + 4 * c);  // uniform addr -> broadcast
            a0 = fmaf(q.x, x[4 * c + 0], a0);
            a1 = fmaf(q.y, x[4 * c + 1], a1);
            a2 = fmaf(q.z, x[4 * c + 2], a2);
            a3 = fmaf(q.w, x[4 * c + 3], a3);
        }
        const float e = (a0 + a1) + (a2 + a3);
        score = fmaf(fmaxf(e, 0.0f), v[h], score);
    }

    scores[(size_t)b * T + t] = score;   // coalesced
}

// ---------------------------------------------------------------------------
// Kernel 3: ragged masked softmax per b, row held in registers (1R + 1W).
// Grid: B blocks x 1024 threads; each thread owns 8 elements.
// ---------------------------------------------------------------------------
#define SM_TPB 1024
#define SM_PER (T / SM_TPB)    // 8

__global__ __launch_bounds__(SM_TPB) void k_softmax(
    float* __restrict__ out,           // [B][T], holds scores on entry
    const int* __restrict__ len_seq)
{
    const int b    = blockIdx.x;
    const int tid  = threadIdx.x;
    const int lane = tid & 63;
    const int wid  = tid >> 6;
    const int len  = len_seq[b];
    float* s = out + (size_t)b * T;

    __shared__ float red[16];

    // --- single read of the row into registers ---
    float val[SM_PER];
#pragma unroll
    for (int i = 0; i < SM_PER; ++i) val[i] = s[tid + i * SM_TPB];

    // --- block max over valid t ---
    float m = -1e30f;
#pragma unroll
    for (int i = 0; i < SM_PER; ++i)
        if (tid + i * SM_TPB < len) m = fmaxf(m, val[i]);
#pragma unroll
    for (int off = 32; off >= 1; off >>= 1) m = fmaxf(m, __shfl_xor(m, off));
    if (lane == 0) red[wid] = m;
    __syncthreads();
    if (wid == 0) {
        float xv = (lane < 16) ? red[lane] : -1e30f;
#pragma unroll
        for (int off = 8; off >= 1; off >>= 1) xv = fmaxf(xv, __shfl_xor(xv, off));
        if (lane == 0) red[0] = xv;
    }
    __syncthreads();
    m = red[0];
    __syncthreads();

    // --- exp + block sum ---
    float sum = 0.0f;
#pragma unroll
    for (int i = 0; i < SM_PER; ++i) {
        const int t = tid + i * SM_TPB;
        val[i] = (t < len) ? __expf(val[i] - m) : 0.0f;
        sum += val[i];
    }
#pragma unroll
    for (int off = 32; off >= 1; off >>= 1) sum += __shfl_xor(sum, off);
    if (lane == 0) red[wid] = sum;
    __syncthreads();
    if (wid == 0) {
        float xv = (lane < 16) ? red[lane] : 0.f;
#pragma unroll
        for (int off = 8; off >= 1; off >>= 1) xv += __shfl_xor(xv, off);
        if (lane == 0) red[0] = xv;
    }
    __syncthreads();
    const float inv = 1.0f / red[0];

    // --- single coalesced write ---
#pragma unroll
    for (int i = 0; i < SM_PER; ++i) s[tid + i * SM_TPB] = val[i] * inv;
}

// ---------------------------------------------------------------------------
extern "C" void kernel_launch(void* const* d_in, const int* in_sizes, int n_in,
                              void* d_out, int out_size, void* d_ws, size_t ws_size,
                              hipStream_t stream) {
    const float* hidden = (const float*)d_in[0];  // [B,H]
    const float* enc    = (const float*)d_in[1];  // [T,B,H]
    const int*   len    = (const int*)d_in[2];    // [B]
    const float* W      = (const float*)d_in[3];  // [H, 2H]
    const float* bb     = (const float*)d_in[4];  // [H]
    const float* v      = (const float*)d_in[5];  // [H]

    float* out  = (float*)d_out;   // [B,1,T] == [B][T]
    float* u_ws = (float*)d_ws;    // B*H floats = 16 KB

    k_precompute_u<<<B, H, 0, stream>>>(hidden, W, bb, u_ws);

    dim3 grid(T / TPB, B);         // (32, 32)
    k_scores<<<grid, TPB, 0, stream>>>(enc, W, u_ws, v, out);

    k_softmax<<<B, SM_TPB, 0, stream>>>(out, len);
}